// Round 9
// baseline (95.136 us; speedup 1.0000x reference)
//
#include <hip/hip_runtime.h>
#include <hip/hip_bf16.h>
#include <math.h>

#define N_ROWS 8192
#define M_ROWS 4096
#define DDIM   512
#define SDIM   16

#define BM 128
#define BN 128
#define BK 64

typedef __attribute__((ext_vector_type(8))) __bf16 bf16x8;
typedef __attribute__((ext_vector_type(4))) float f32x4;

__device__ __forceinline__ unsigned short f2bf_rne(float f) {
  unsigned u = __float_as_uint(f);
  u += 0x7fffu + ((u >> 16) & 1u);
  return (unsigned short)(u >> 16);
}

__device__ __forceinline__ void load_lds16(const void* g, void* l) {
  __builtin_amdgcn_global_load_lds(
      (const __attribute__((address_space(1))) void*)g,
      (__attribute__((address_space(3))) void*)l, 16, 0, 0);
}

// One row per WAVE (4 rows per 256-thread block) — R8-proven.
__global__ __launch_bounds__(256) void prep_kernel(
    const float* __restrict__ x, const float* __restrict__ y,
    const float* __restrict__ samp_x, const float* __restrict__ samp_y,
    const float* __restrict__ scale,
    ushort* __restrict__ xb, ushort* __restrict__ yb,
    float* __restrict__ sqx, float* __restrict__ sqy,
    float* __restrict__ ssx, float* __restrict__ ssy)
{
  const int tid  = threadIdx.x;
  const int lane = tid & 63;
  const int row  = blockIdx.x * 4 + (tid >> 6);

  const float* src; const float* samp; ushort* dst; float* sqo; float* sso;
  if (row < N_ROWS) {
    src = x + (size_t)row * DDIM; samp = samp_x + (size_t)row * SDIM;
    dst = xb + (size_t)row * DDIM; sqo = sqx + row; sso = ssx + row;
  } else {
    int r = row - N_ROWS;
    src = y + (size_t)r * DDIM; samp = samp_y + (size_t)r * SDIM;
    dst = yb + (size_t)r * DDIM; sqo = sqy + r; sso = ssy + r;
  }

  const float4 v0 = ((const float4*)src)[lane * 2];
  const float4 v1 = ((const float4*)src)[lane * 2 + 1];
  uint4 pk;
  pk.x = (unsigned)f2bf_rne(v0.x) | ((unsigned)f2bf_rne(v0.y) << 16);
  pk.y = (unsigned)f2bf_rne(v0.z) | ((unsigned)f2bf_rne(v0.w) << 16);
  pk.z = (unsigned)f2bf_rne(v1.x) | ((unsigned)f2bf_rne(v1.y) << 16);
  pk.w = (unsigned)f2bf_rne(v1.z) | ((unsigned)f2bf_rne(v1.w) << 16);
  ((uint4*)dst)[lane] = pk;

  float ss = v0.x * v0.x + v0.y * v0.y + v0.z * v0.z + v0.w * v0.w
           + v1.x * v1.x + v1.y * v1.y + v1.z * v1.z + v1.w * v1.w;
  #pragma unroll
  for (int m = 32; m >= 1; m >>= 1) ss += __shfl_xor(ss, m, 64);

  float p = (lane < SDIM) ? samp[lane] * scale[lane] : 0.f;
  #pragma unroll
  for (int m = 8; m >= 1; m >>= 1) p += __shfl_xor(p, m, 64);

  if (lane == 0) {
    *sqo = ss;
    float sp = (p > 15.f) ? p : log1pf(expf(p));   // softplus
    sp = fminf(fmaxf(sp, 1e-10f), 10000.f);
    *sso = sqrtf(sp);
  }
}

// R6 skeleton (single-buffered, 2 __syncthreads/tile, chunked XCD swizzle),
// with A-STAGING REMOVED: each wave loads its 8 A-fragments per K-tile
// directly from global (XCD-local L2 panel) into VGPRs — issued BEFORE the
// barrier so the staging drain covers their latency. Identical element
// mapping to the LDS path (row*512 + t*64 + kk*32 + l16*8, 16B contiguous).
// B stays on the proven swizzled global_load_lds path (16 KiB LDS).
// DS-pipe bytes halved; occupancy regime preserved (~12-16 waves/CU).
__global__ __launch_bounds__(256, 3) void cauchy_gemm(
    const ushort* __restrict__ xb, const ushort* __restrict__ yb,
    const float* __restrict__ sqx, const float* __restrict__ sqy,
    const float* __restrict__ ssx, const float* __restrict__ ssy,
    const float* __restrict__ cutoff, const float* __restrict__ phi,
    float* __restrict__ out)
{
  __shared__ ushort Bs[BN * BK];   // 16 KiB
  const int tid = threadIdx.x;
  const int lane = tid & 63;
  const int w = tid >> 6;
  const int wr = w >> 1, wc = w & 1;
  const int l15 = lane & 15, l16 = lane >> 4;

  const int bid   = blockIdx.x;
  const int xcd   = bid & 7;
  const int local = bid >> 3;
  const int wk    = local & 31;
  const int bx = xcd * 8 + (wk & 7);           // 64 row-blocks; bx in [8k,8k+8)
  const int by = (local >> 5) * 4 + (wk >> 3); // 32 col-blocks

  const size_t bBase = (size_t)by * BN * DDIM;

  // A-fragment row pointers (per-lane): frag a covers row rowBase+a*16+l15,
  // 16B at k-offset l16*8 within each 32-slice.
  const ushort* aP[4];
  #pragma unroll
  for (int a = 0; a < 4; a++)
    aP[a] = xb + (size_t)(bx * BM + wr * 64 + a * 16 + l15) * DDIM + l16 * 8;

  f32x4 acc[4][4];
  #pragma unroll
  for (int a = 0; a < 4; a++)
    #pragma unroll
    for (int b = 0; b < 4; b++)
      acc[a][b] = (f32x4)(0.f);

  for (int k0 = 0; k0 < DDIM; k0 += BK) {
    // stage B tile: 1024 16B-granules, 4 per thread (swizzled source)
    #pragma unroll
    for (int c = 0; c < 4; c++) {
      int idx = c * 256 + tid;
      int row = idx >> 3;
      int g = idx & 7;
      int sg = g ^ (row & 7);            // pre-swizzle the SOURCE granule
      load_lds16(yb + bBase + (size_t)row * DDIM + k0 + sg * 8, Bs + idx * 8);
    }
    // A fragments direct from global (L2-resident panel) — issue pre-barrier
    bf16x8 af[2][4];
    #pragma unroll
    for (int kk = 0; kk < 2; kk++)
      #pragma unroll
      for (int a = 0; a < 4; a++)
        af[kk][a] = *(const bf16x8*)(aP[a] + k0 + kk * 32);

    __syncthreads();  // drain (covers B staging AND the A loads) + barrier

    #pragma unroll
    for (int kk = 0; kk < 2; kk++) {
      bf16x8 bfr[4];
      #pragma unroll
      for (int b = 0; b < 4; b++) {
        int col = wc * 64 + b * 16 + l15;
        int gran = kk * 4 + l16;
        int off = col * BK + ((gran ^ (col & 7)) << 3);
        bfr[b] = *(const bf16x8*)((const char*)Bs + (size_t)off * 2);
      }
      #pragma unroll
      for (int a = 0; a < 4; a++)
        #pragma unroll
        for (int b = 0; b < 4; b++)
          acc[a][b] = __builtin_amdgcn_mfma_f32_16x16x32_bf16(af[kk][a], bfr[b], acc[a][b], 0, 0, 0);
    }
    __syncthreads();
  }

  // ---- fused epilogue (R6-proven) ----
  const float cut_c = fminf(fmaxf(cutoff[0], 0.f), 1000.f);
  const float q  = phi[0] * 1.4426950408889634f;   // phi * log2(e)
  const float qc = q * cut_c;
  const int rowBase = bx * BM + wr * 64;
  const int colBase = by * BN + wc * 64;

  float sq_j[4], sy_j[4];
  #pragma unroll
  for (int b = 0; b < 4; b++) {
    int j = colBase + b * 16 + l15;
    sq_j[b] = sqy[j];
    sy_j[b] = ssy[j];
  }
  #pragma unroll
  for (int a = 0; a < 4; a++) {
    float sq_i[4], sx_i[4];
    #pragma unroll
    for (int r = 0; r < 4; r++) {
      int i = rowBase + a * 16 + l16 * 4 + r;
      sq_i[r] = sqx[i];
      sx_i[r] = ssx[i];
    }
    #pragma unroll
    for (int b = 0; b < 4; b++) {
      #pragma unroll
      for (int r = 0; r < 4; r++) {
        int i = rowBase + a * 16 + l16 * 4 + r;
        int j = colBase + b * 16 + l15;
        float dot = acc[a][b][r];
        float d = __builtin_fmaf(-2.f, dot, sq_i[r] + sq_j[b]);
        float s = sx_i[r] * sy_j[b];
        float res = s * __builtin_amdgcn_rcpf(s + d);     // 1/(1+d/s)
        float earg = __builtin_fmaf(-q, res, qc);         // -phi*(res-cut)*log2e
        float u = __builtin_amdgcn_exp2f(earg);
        float o = res * __builtin_amdgcn_rcpf(1.f + u);   // res * sigmoid
        out[(size_t)i * M_ROWS + j] = o;
      }
    }
  }
}

extern "C" void kernel_launch(void* const* d_in, const int* in_sizes, int n_in,
                              void* d_out, int out_size, void* d_ws, size_t ws_size,
                              hipStream_t stream) {
  const float* x       = (const float*)d_in[0];
  const float* y       = (const float*)d_in[1];
  const float* samp_x  = (const float*)d_in[2];
  const float* samp_y  = (const float*)d_in[3];
  const float* scale   = (const float*)d_in[4];
  const float* cutoff  = (const float*)d_in[5];
  const float* phi     = (const float*)d_in[6];
  float* out = (float*)d_out;

  char* p = (char*)d_ws;
  ushort* xb = (ushort*)p; p += (size_t)N_ROWS * DDIM * 2;
  ushort* yb = (ushort*)p; p += (size_t)M_ROWS * DDIM * 2;
  float* sqx = (float*)p;  p += (size_t)N_ROWS * 4;
  float* sqy = (float*)p;  p += (size_t)M_ROWS * 4;
  float* ssx = (float*)p;  p += (size_t)N_ROWS * 4;
  float* ssy = (float*)p;  p += (size_t)M_ROWS * 4;

  prep_kernel<<<(N_ROWS + M_ROWS) / 4, 256, 0, stream>>>(
      x, y, samp_x, samp_y, scale, xb, yb, sqx, sqy, ssx, ssy);

  cauchy_gemm<<<(N_ROWS / BM) * (M_ROWS / BN), 256, 0, stream>>>(
      xb, yb, sqx, sqy, ssx, ssy, cutoff, phi, out);
}

// Round 10
// 92.501 us; speedup vs baseline: 1.0285x; 1.0285x over previous
//
#include <hip/hip_runtime.h>
#include <hip/hip_bf16.h>
#include <math.h>

#define N_ROWS 8192
#define M_ROWS 4096
#define DDIM   512
#define SDIM   16

#define BM 128
#define BN 256
#define BK 64

typedef __attribute__((ext_vector_type(8))) __bf16 bf16x8;
typedef __attribute__((ext_vector_type(4))) float f32x4;

__device__ __forceinline__ unsigned short f2bf_rne(float f) {
  unsigned u = __float_as_uint(f);
  u += 0x7fffu + ((u >> 16) & 1u);
  return (unsigned short)(u >> 16);
}

__device__ __forceinline__ void load_lds16(const void* g, void* l) {
  __builtin_amdgcn_global_load_lds(
      (const __attribute__((address_space(1))) void*)g,
      (__attribute__((address_space(3))) void*)l, 16, 0, 0);
}

// One row per WAVE (4 rows per 256-thread block) — R8-proven.
__global__ __launch_bounds__(256) void prep_kernel(
    const float* __restrict__ x, const float* __restrict__ y,
    const float* __restrict__ samp_x, const float* __restrict__ samp_y,
    const float* __restrict__ scale,
    ushort* __restrict__ xb, ushort* __restrict__ yb,
    float* __restrict__ sqx, float* __restrict__ sqy,
    float* __restrict__ ssx, float* __restrict__ ssy)
{
  const int tid  = threadIdx.x;
  const int lane = tid & 63;
  const int row  = blockIdx.x * 4 + (tid >> 6);

  const float* src; const float* samp; ushort* dst; float* sqo; float* sso;
  if (row < N_ROWS) {
    src = x + (size_t)row * DDIM; samp = samp_x + (size_t)row * SDIM;
    dst = xb + (size_t)row * DDIM; sqo = sqx + row; sso = ssx + row;
  } else {
    int r = row - N_ROWS;
    src = y + (size_t)r * DDIM; samp = samp_y + (size_t)r * SDIM;
    dst = yb + (size_t)r * DDIM; sqo = sqy + r; sso = ssy + r;
  }

  const float4 v0 = ((const float4*)src)[lane * 2];
  const float4 v1 = ((const float4*)src)[lane * 2 + 1];
  uint4 pk;
  pk.x = (unsigned)f2bf_rne(v0.x) | ((unsigned)f2bf_rne(v0.y) << 16);
  pk.y = (unsigned)f2bf_rne(v0.z) | ((unsigned)f2bf_rne(v0.w) << 16);
  pk.z = (unsigned)f2bf_rne(v1.x) | ((unsigned)f2bf_rne(v1.y) << 16);
  pk.w = (unsigned)f2bf_rne(v1.z) | ((unsigned)f2bf_rne(v1.w) << 16);
  ((uint4*)dst)[lane] = pk;

  float ss = v0.x * v0.x + v0.y * v0.y + v0.z * v0.z + v0.w * v0.w
           + v1.x * v1.x + v1.y * v1.y + v1.z * v1.z + v1.w * v1.w;
  #pragma unroll
  for (int m = 32; m >= 1; m >>= 1) ss += __shfl_xor(ss, m, 64);

  float p = (lane < SDIM) ? samp[lane] * scale[lane] : 0.f;
  #pragma unroll
  for (int m = 8; m >= 1; m >>= 1) p += __shfl_xor(p, m, 64);

  if (lane == 0) {
    *sqo = ss;
    float sp = (p > 15.f) ? p : log1pf(expf(p));   // softplus
    sp = fminf(fmaxf(sp, 1e-10f), 10000.f);
    *sso = sqrtf(sp);
  }
}

// R6 structure, widened: 128x256 block tile, BK=64, 4 waves side-by-side
// (wave tile 128x64: acc[8][4] in AGPRs, A ds_reads wave-uniform rows),
// SINGLE-buffered 48 KiB LDS, two __syncthreads per tile. MFMA:ds_read
// ratio 2.67 (was 2.0); staged-L2 bytes and ds_read bytes -25%/FLOP;
// half the blocks -> per-block fixed cost amortized 2x (K=512 is short).
// XOR swizzle g^(row&7) on BOTH global source and ds_read (rule #21).
// Chunked XCD swizzle: XCD k owns bx in [8k,8k+8) for all by.
__global__ __launch_bounds__(256) void cauchy_gemm(
    const ushort* __restrict__ xb, const ushort* __restrict__ yb,
    const float* __restrict__ sqx, const float* __restrict__ sqy,
    const float* __restrict__ ssx, const float* __restrict__ ssy,
    const float* __restrict__ cutoff, const float* __restrict__ phi,
    float* __restrict__ out)
{
  __shared__ ushort As[BM * BK];   // 16 KiB
  __shared__ ushort Bs[BN * BK];   // 32 KiB
  const int tid = threadIdx.x;
  const int lane = tid & 63;
  const int w = tid >> 6;          // wave 0..3 -> col quarter
  const int l15 = lane & 15, l16 = lane >> 4;

  // chunked XCD swizzle: 1024 blocks; xcd = bid&7, local = bid>>3 (0..127).
  const int bid   = blockIdx.x;
  const int xcd   = bid & 7;
  const int local = bid >> 3;
  const int wk    = local & 31;
  const int bx = xcd * 8 + (wk & 7);           // 64 row-blocks; bx in [8k,8k+8)
  const int by = (local >> 5) * 4 + (wk >> 3); // 16 col-blocks

  const size_t aBase = (size_t)bx * BM * DDIM;
  const size_t bBase = (size_t)by * BN * DDIM;

  f32x4 acc[8][4];
  #pragma unroll
  for (int a = 0; a < 8; a++)
    #pragma unroll
    for (int b = 0; b < 4; b++)
      acc[a][b] = (f32x4)(0.f);

  for (int k0 = 0; k0 < DDIM; k0 += BK) {
    // stage A (1024 granules, 4/thread) and B (2048 granules, 8/thread)
    #pragma unroll
    for (int c = 0; c < 4; c++) {
      int idx = c * 256 + tid;
      int row = idx >> 3, g = idx & 7;
      int sg = g ^ (row & 7);            // pre-swizzle the SOURCE granule
      load_lds16(xb + aBase + (size_t)row * DDIM + k0 + sg * 8, As + idx * 8);
    }
    #pragma unroll
    for (int c = 0; c < 8; c++) {
      int idx = c * 256 + tid;
      int row = idx >> 3, g = idx & 7;
      int sg = g ^ (row & 7);
      load_lds16(yb + bBase + (size_t)row * DDIM + k0 + sg * 8, Bs + idx * 8);
    }
    __syncthreads();  // vmcnt(0) drain + barrier

    #pragma unroll
    for (int kk = 0; kk < 2; kk++) {
      bf16x8 af[8], bfr[4];
      #pragma unroll
      for (int a = 0; a < 8; a++) {
        int row = a * 16 + l15;                          // wave-uniform rows
        int gran = kk * 4 + l16;
        int off = row * BK + ((gran ^ (row & 7)) << 3);  // elements
        af[a] = *(const bf16x8*)((const char*)As + (size_t)off * 2);
      }
      #pragma unroll
      for (int b = 0; b < 4; b++) {
        int col = w * 64 + b * 16 + l15;
        int gran = kk * 4 + l16;
        int off = col * BK + ((gran ^ (col & 7)) << 3);
        bfr[b] = *(const bf16x8*)((const char*)Bs + (size_t)off * 2);
      }
      #pragma unroll
      for (int a = 0; a < 8; a++)
        #pragma unroll
        for (int b = 0; b < 4; b++)
          acc[a][b] = __builtin_amdgcn_mfma_f32_16x16x32_bf16(af[a], bfr[b], acc[a][b], 0, 0, 0);
    }
    __syncthreads();
  }

  // ---- fused epilogue (R6-proven math) ----
  const float cut_c = fminf(fmaxf(cutoff[0], 0.f), 1000.f);
  const float q  = phi[0] * 1.4426950408889634f;   // phi * log2(e)
  const float qc = q * cut_c;
  const int rowBase = bx * BM;
  const int colBase = by * BN + w * 64;

  float sq_j[4], sy_j[4];
  #pragma unroll
  for (int b = 0; b < 4; b++) {
    int j = colBase + b * 16 + l15;
    sq_j[b] = sqy[j];
    sy_j[b] = ssy[j];
  }
  #pragma unroll
  for (int a = 0; a < 8; a++) {
    float sq_i[4], sx_i[4];
    #pragma unroll
    for (int r = 0; r < 4; r++) {
      int i = rowBase + a * 16 + l16 * 4 + r;
      sq_i[r] = sqx[i];
      sx_i[r] = ssx[i];
    }
    #pragma unroll
    for (int b = 0; b < 4; b++) {
      #pragma unroll
      for (int r = 0; r < 4; r++) {
        int i = rowBase + a * 16 + l16 * 4 + r;
        int j = colBase + b * 16 + l15;
        float dot = acc[a][b][r];
        float d = __builtin_fmaf(-2.f, dot, sq_i[r] + sq_j[b]);
        float s = sx_i[r] * sy_j[b];
        float res = s * __builtin_amdgcn_rcpf(s + d);     // 1/(1+d/s)
        float earg = __builtin_fmaf(-q, res, qc);         // -phi*(res-cut)*log2e
        float u = __builtin_amdgcn_exp2f(earg);
        float o = res * __builtin_amdgcn_rcpf(1.f + u);   // res * sigmoid
        out[(size_t)i * M_ROWS + j] = o;
      }
    }
  }
}

extern "C" void kernel_launch(void* const* d_in, const int* in_sizes, int n_in,
                              void* d_out, int out_size, void* d_ws, size_t ws_size,
                              hipStream_t stream) {
  const float* x       = (const float*)d_in[0];
  const float* y       = (const float*)d_in[1];
  const float* samp_x  = (const float*)d_in[2];
  const float* samp_y  = (const float*)d_in[3];
  const float* scale   = (const float*)d_in[4];
  const float* cutoff  = (const float*)d_in[5];
  const float* phi     = (const float*)d_in[6];
  float* out = (float*)d_out;

  char* p = (char*)d_ws;
  ushort* xb = (ushort*)p; p += (size_t)N_ROWS * DDIM * 2;
  ushort* yb = (ushort*)p; p += (size_t)M_ROWS * DDIM * 2;
  float* sqx = (float*)p;  p += (size_t)N_ROWS * 4;
  float* sqy = (float*)p;  p += (size_t)M_ROWS * 4;
  float* ssx = (float*)p;  p += (size_t)N_ROWS * 4;
  float* ssy = (float*)p;  p += (size_t)M_ROWS * 4;

  prep_kernel<<<(N_ROWS + M_ROWS) / 4, 256, 0, stream>>>(
      x, y, samp_x, samp_y, scale, xb, yb, sqx, sqy, ssx, ssy);

  cauchy_gemm<<<(N_ROWS / BM) * (M_ROWS / BN), 256, 0, stream>>>(
      xb, yb, sqx, sqy, ssx, ssy, cutoff, phi, out);
}

// Round 11
// 76.995 us; speedup vs baseline: 1.2356x; 1.2014x over previous
//
#include <hip/hip_runtime.h>
#include <hip/hip_bf16.h>
#include <math.h>

#define N_ROWS 8192
#define M_ROWS 4096
#define DDIM   512
#define SDIM   16

#define BM 128
#define BN 128
#define BKS 32              // K per pipeline step
#define NSTEP (DDIM / BKS)  // 16 steps

typedef __attribute__((ext_vector_type(8))) __bf16 bf16x8;
typedef __attribute__((ext_vector_type(4))) float f32x4;

__device__ __forceinline__ unsigned short f2bf_rne(float f) {
  unsigned u = __float_as_uint(f);
  u += 0x7fffu + ((u >> 16) & 1u);
  return (unsigned short)(u >> 16);
}

__device__ __forceinline__ void load_lds16(const void* g, void* l) {
  __builtin_amdgcn_global_load_lds(
      (const __attribute__((address_space(1))) void*)g,
      (__attribute__((address_space(3))) void*)l, 16, 0, 0);
}

// One row per WAVE (4 rows per 256-thread block) — R8-proven.
__global__ __launch_bounds__(256) void prep_kernel(
    const float* __restrict__ x, const float* __restrict__ y,
    const float* __restrict__ samp_x, const float* __restrict__ samp_y,
    const float* __restrict__ scale,
    ushort* __restrict__ xb, ushort* __restrict__ yb,
    float* __restrict__ sqx, float* __restrict__ sqy,
    float* __restrict__ ssx, float* __restrict__ ssy)
{
  const int tid  = threadIdx.x;
  const int lane = tid & 63;
  const int row  = blockIdx.x * 4 + (tid >> 6);

  const float* src; const float* samp; ushort* dst; float* sqo; float* sso;
  if (row < N_ROWS) {
    src = x + (size_t)row * DDIM; samp = samp_x + (size_t)row * SDIM;
    dst = xb + (size_t)row * DDIM; sqo = sqx + row; sso = ssx + row;
  } else {
    int r = row - N_ROWS;
    src = y + (size_t)r * DDIM; samp = samp_y + (size_t)r * SDIM;
    dst = yb + (size_t)r * DDIM; sqo = sqy + r; sso = ssy + r;
  }

  const float4 v0 = ((const float4*)src)[lane * 2];
  const float4 v1 = ((const float4*)src)[lane * 2 + 1];
  uint4 pk;
  pk.x = (unsigned)f2bf_rne(v0.x) | ((unsigned)f2bf_rne(v0.y) << 16);
  pk.y = (unsigned)f2bf_rne(v0.z) | ((unsigned)f2bf_rne(v0.w) << 16);
  pk.z = (unsigned)f2bf_rne(v1.x) | ((unsigned)f2bf_rne(v1.y) << 16);
  pk.w = (unsigned)f2bf_rne(v1.z) | ((unsigned)f2bf_rne(v1.w) << 16);
  ((uint4*)dst)[lane] = pk;

  float ss = v0.x * v0.x + v0.y * v0.y + v0.z * v0.z + v0.w * v0.w
           + v1.x * v1.x + v1.y * v1.y + v1.z * v1.z + v1.w * v1.w;
  #pragma unroll
  for (int m = 32; m >= 1; m >>= 1) ss += __shfl_xor(ss, m, 64);

  float p = (lane < SDIM) ? samp[lane] * scale[lane] : 0.f;
  #pragma unroll
  for (int m = 8; m >= 1; m >>= 1) p += __shfl_xor(p, m, 64);

  if (lane == 0) {
    *sqo = ss;
    float sp = (p > 15.f) ? p : log1pf(expf(p));   // softplus
    sp = fminf(fmaxf(sp, 1e-10f), 10000.f);
    *sso = sqrtf(sp);
  }
}

// 128x128 GEMM + fused Cauchy epilogue.
// 3-STAGE counted-vmcnt pipeline (never drain to 0): BKS=32, 16 steps,
// 3 LDS buffer sets (48 KiB -> 3 blocks/CU). Step s: stage step s+2 into
// buf[(s+2)%3] (4 global_load_lds), ds_read 8 frags + 16 MFMA on buf[s%3],
// then vmcnt(4) — waits ONLY for stage s+1 (issued one full step earlier,
// ~350 cyc of compute to hide ~250-cyc L2 latency) while s+2 stays in
// flight — then one barrier. Race-safe: buf staged at s was last read at
// s-1, whose reads retire before its end barrier.
// Swizzle g' = g ^ ((row>>1)&3) on BOTH global source and ds_read (rule #21).
// Chunked XCD mapping (R6-proven): XCD k owns bx in [8k,8k+8) for all by.
__global__ __launch_bounds__(256) void cauchy_gemm(
    const ushort* __restrict__ xb, const ushort* __restrict__ yb,
    const float* __restrict__ sqx, const float* __restrict__ sqy,
    const float* __restrict__ ssx, const float* __restrict__ ssy,
    const float* __restrict__ cutoff, const float* __restrict__ phi,
    float* __restrict__ out)
{
  __shared__ ushort As[3][BM * BKS];   // 3 x 8 KiB
  __shared__ ushort Bs[3][BN * BKS];   // 3 x 8 KiB   (48 KiB total)

  const int tid  = threadIdx.x;
  const int lane = tid & 63;
  const int w    = tid >> 6;
  const int wr = w >> 1, wc = w & 1;
  const int l15 = lane & 15, l16 = lane >> 4;

  // chunked XCD swizzle (R6): xcd = bid&7, local = bid>>3.
  const int bid   = blockIdx.x;
  const int xcd   = bid & 7;
  const int local = bid >> 3;
  const int wk    = local & 31;
  const int bx = xcd * 8 + (wk & 7);           // 64 row-blocks; bx in [8k,8k+8)
  const int by = (local >> 5) * 4 + (wk >> 3); // 32 col-blocks

  // staging: 512 granules (16B) per matrix per step, 2 per thread
  const int i0 = tid, i1 = tid + 256;
  const int r0 = i0 >> 2, r1 = i1 >> 2;
  const int c0 = (i0 & 3) ^ ((r0 >> 1) & 3);   // pre-swizzled source granule
  const int c1 = (i1 & 3) ^ ((r1 >> 1) & 3);
  const ushort* aS0 = xb + (size_t)(bx * BM + r0) * DDIM + c0 * 8;
  const ushort* aS1 = xb + (size_t)(bx * BM + r1) * DDIM + c1 * 8;
  const ushort* bS0 = yb + (size_t)(by * BN + r0) * DDIM + c0 * 8;
  const ushort* bS1 = yb + (size_t)(by * BN + r1) * DDIM + c1 * 8;
  const int d0 = i0 * 8, d1 = i1 * 8;          // linear LDS dest (elements)

  // fragment ds_read offsets (loop-invariant, swizzled)
  int aoff[4], boff[4];
  #pragma unroll
  for (int a = 0; a < 4; a++) {
    int row = wr * 64 + a * 16 + l15;
    aoff[a] = row * BKS + ((l16 ^ ((row >> 1) & 3)) << 3);
  }
  #pragma unroll
  for (int b = 0; b < 4; b++) {
    int col = wc * 64 + b * 16 + l15;
    boff[b] = col * BKS + ((l16 ^ ((col >> 1) & 3)) << 3);
  }

  f32x4 acc[4][4];
  #pragma unroll
  for (int a = 0; a < 4; a++)
    #pragma unroll
    for (int b = 0; b < 4; b++) acc[a][b] = (f32x4)(0.f);

  // prologue: stage steps 0 and 1; wait for step 0 only (step 1 in flight)
  load_lds16(aS0, &As[0][d0]); load_lds16(aS1, &As[0][d1]);
  load_lds16(bS0, &Bs[0][d0]); load_lds16(bS1, &Bs[0][d1]);
  load_lds16(aS0 + BKS, &As[1][d0]); load_lds16(aS1 + BKS, &As[1][d1]);
  load_lds16(bS0 + BKS, &Bs[1][d0]); load_lds16(bS1 + BKS, &Bs[1][d1]);
  asm volatile("s_waitcnt vmcnt(4)" ::: "memory");
  __builtin_amdgcn_s_barrier();

  int cur = 0;
  for (int s = 0; s < NSTEP; ++s) {
    int nxt = cur + 2; if (nxt >= 3) nxt -= 3;
    if (s + 2 < NSTEP) {           // stage step s+2 (read last at step s-1)
      const int ko = (s + 2) * BKS;
      load_lds16(aS0 + ko, &As[nxt][d0]);
      load_lds16(aS1 + ko, &As[nxt][d1]);
      load_lds16(bS0 + ko, &Bs[nxt][d0]);
      load_lds16(bS1 + ko, &Bs[nxt][d1]);
    }
    bf16x8 af[4], bf[4];
    #pragma unroll
    for (int a = 0; a < 4; a++) af[a] = *(const bf16x8*)&As[cur][aoff[a]];
    #pragma unroll
    for (int b = 0; b < 4; b++) bf[b] = *(const bf16x8*)&Bs[cur][boff[b]];

    __builtin_amdgcn_s_setprio(1);
    #pragma unroll
    for (int a = 0; a < 4; a++)
      #pragma unroll
      for (int b = 0; b < 4; b++)
        acc[a][b] = __builtin_amdgcn_mfma_f32_16x16x32_bf16(af[a], bf[b], acc[a][b], 0, 0, 0);
    __builtin_amdgcn_s_setprio(0);

    if (s < NSTEP - 2) {
      asm volatile("s_waitcnt vmcnt(4)" ::: "memory");  // s+1 landed; s+2 in flight
      __builtin_amdgcn_s_barrier();
    } else if (s == NSTEP - 2) {
      asm volatile("s_waitcnt vmcnt(0)" ::: "memory");  // last stage landed
      __builtin_amdgcn_s_barrier();
    }
    cur = cur + 1; if (cur >= 3) cur -= 3;
  }

  // ---- fused epilogue (R6-proven) ----
  const float cut_c = fminf(fmaxf(cutoff[0], 0.f), 1000.f);
  const float q  = phi[0] * 1.4426950408889634f;   // phi * log2(e)
  const float qc = q * cut_c;
  const int rowBase = bx * BM + wr * 64;
  const int colBase = by * BN + wc * 64;

  float sq_j[4], sy_j[4];
  #pragma unroll
  for (int b = 0; b < 4; b++) {
    int j = colBase + b * 16 + l15;
    sq_j[b] = sqy[j];
    sy_j[b] = ssy[j];
  }
  #pragma unroll
  for (int a = 0; a < 4; a++) {
    float sq_i[4], sx_i[4];
    #pragma unroll
    for (int r = 0; r < 4; r++) {
      int i = rowBase + a * 16 + l16 * 4 + r;
      sq_i[r] = sqx[i];
      sx_i[r] = ssx[i];
    }
    #pragma unroll
    for (int b = 0; b < 4; b++) {
      #pragma unroll
      for (int r = 0; r < 4; r++) {
        int i = rowBase + a * 16 + l16 * 4 + r;
        int j = colBase + b * 16 + l15;
        float dot = acc[a][b][r];
        float d = __builtin_fmaf(-2.f, dot, sq_i[r] + sq_j[b]);
        float s = sx_i[r] * sy_j[b];
        float res = s * __builtin_amdgcn_rcpf(s + d);     // 1/(1+d/s)
        float earg = __builtin_fmaf(-q, res, qc);         // -phi*(res-cut)*log2e
        float u = __builtin_amdgcn_exp2f(earg);
        float o = res * __builtin_amdgcn_rcpf(1.f + u);   // res * sigmoid
        out[(size_t)i * M_ROWS + j] = o;
      }
    }
  }
}

extern "C" void kernel_launch(void* const* d_in, const int* in_sizes, int n_in,
                              void* d_out, int out_size, void* d_ws, size_t ws_size,
                              hipStream_t stream) {
  const float* x       = (const float*)d_in[0];
  const float* y       = (const float*)d_in[1];
  const float* samp_x  = (const float*)d_in[2];
  const float* samp_y  = (const float*)d_in[3];
  const float* scale   = (const float*)d_in[4];
  const float* cutoff  = (const float*)d_in[5];
  const float* phi     = (const float*)d_in[6];
  float* out = (float*)d_out;

  char* p = (char*)d_ws;
  ushort* xb = (ushort*)p; p += (size_t)N_ROWS * DDIM * 2;
  ushort* yb = (ushort*)p; p += (size_t)M_ROWS * DDIM * 2;
  float* sqx = (float*)p;  p += (size_t)N_ROWS * 4;
  float* sqy = (float*)p;  p += (size_t)M_ROWS * 4;
  float* ssx = (float*)p;  p += (size_t)N_ROWS * 4;
  float* ssy = (float*)p;  p += (size_t)M_ROWS * 4;

  prep_kernel<<<(N_ROWS + M_ROWS) / 4, 256, 0, stream>>>(
      x, y, samp_x, samp_y, scale, xb, yb, sqx, sqy, ssx, ssy);

  cauchy_gemm<<<(N_ROWS / BM) * (M_ROWS / BN), 256, 0, stream>>>(
      xb, yb, sqx, sqy, ssx, ssy, cutoff, phi, out);
}

// Round 12
// 73.888 us; speedup vs baseline: 1.2876x; 1.0420x over previous
//
#include <hip/hip_runtime.h>
#include <hip/hip_bf16.h>
#include <math.h>

#define N_ROWS 8192
#define M_ROWS 4096
#define DDIM   512
#define SDIM   16

#define BM 128
#define BN 128
#define BKS 32              // K per tile-step (one MFMA K-slice)
#define NSTEP (DDIM / BKS)  // 16 steps

typedef __attribute__((ext_vector_type(8))) __bf16 bf16x8;
typedef __attribute__((ext_vector_type(4))) float f32x4;

__device__ __forceinline__ unsigned short f2bf_rne(float f) {
  unsigned u = __float_as_uint(f);
  u += 0x7fffu + ((u >> 16) & 1u);
  return (unsigned short)(u >> 16);
}

__device__ __forceinline__ void load_lds16(const void* g, void* l) {
  __builtin_amdgcn_global_load_lds(
      (const __attribute__((address_space(1))) void*)g,
      (__attribute__((address_space(3))) void*)l, 16, 0, 0);
}

// One row per WAVE (4 rows per 256-thread block) — R8-proven.
__global__ __launch_bounds__(256) void prep_kernel(
    const float* __restrict__ x, const float* __restrict__ y,
    const float* __restrict__ samp_x, const float* __restrict__ samp_y,
    const float* __restrict__ scale,
    ushort* __restrict__ xb, ushort* __restrict__ yb,
    float* __restrict__ sqx, float* __restrict__ sqy,
    float* __restrict__ ssx, float* __restrict__ ssy)
{
  const int tid  = threadIdx.x;
  const int lane = tid & 63;
  const int row  = blockIdx.x * 4 + (tid >> 6);

  const float* src; const float* samp; ushort* dst; float* sqo; float* sso;
  if (row < N_ROWS) {
    src = x + (size_t)row * DDIM; samp = samp_x + (size_t)row * SDIM;
    dst = xb + (size_t)row * DDIM; sqo = sqx + row; sso = ssx + row;
  } else {
    int r = row - N_ROWS;
    src = y + (size_t)r * DDIM; samp = samp_y + (size_t)r * SDIM;
    dst = yb + (size_t)r * DDIM; sqo = sqy + r; sso = ssy + r;
  }

  const float4 v0 = ((const float4*)src)[lane * 2];
  const float4 v1 = ((const float4*)src)[lane * 2 + 1];
  uint4 pk;
  pk.x = (unsigned)f2bf_rne(v0.x) | ((unsigned)f2bf_rne(v0.y) << 16);
  pk.y = (unsigned)f2bf_rne(v0.z) | ((unsigned)f2bf_rne(v0.w) << 16);
  pk.z = (unsigned)f2bf_rne(v1.x) | ((unsigned)f2bf_rne(v1.y) << 16);
  pk.w = (unsigned)f2bf_rne(v1.z) | ((unsigned)f2bf_rne(v1.w) << 16);
  ((uint4*)dst)[lane] = pk;

  float ss = v0.x * v0.x + v0.y * v0.y + v0.z * v0.z + v0.w * v0.w
           + v1.x * v1.x + v1.y * v1.y + v1.z * v1.z + v1.w * v1.w;
  #pragma unroll
  for (int m = 32; m >= 1; m >>= 1) ss += __shfl_xor(ss, m, 64);

  float p = (lane < SDIM) ? samp[lane] * scale[lane] : 0.f;
  #pragma unroll
  for (int m = 8; m >= 1; m >>= 1) p += __shfl_xor(p, m, 64);

  if (lane == 0) {
    *sqo = ss;
    float sp = (p > 15.f) ? p : log1pf(expf(p));   // softplus
    sp = fminf(fmaxf(sp, 1e-10f), 10000.f);
    *sso = sqrtf(sp);
  }
}

// R6/R8 phase-separated structure with BK=32 single buffer (16 KiB LDS):
// per step: stage 16 KiB (4 gload_lds/thread-group), __syncthreads (drain),
// 8 swizzled ds_read_b128 + 16 MFMA, __syncthreads. LDS occupancy cap rises
// 5 -> 8 resident blocks; each drain's staged bytes halve. No inline-asm
// barriers (compiler schedules ds_read->MFMA waits optimally around
// __syncthreads). XOR swizzle g^((row>>1)&3) on BOTH global source and
// ds_read address (rule #21; 2-way residual = free).
// Chunked XCD mapping (R6-proven): XCD k owns bx in [8k,8k+8) for all by.
__global__ __launch_bounds__(256) void cauchy_gemm(
    const ushort* __restrict__ xb, const ushort* __restrict__ yb,
    const float* __restrict__ sqx, const float* __restrict__ sqy,
    const float* __restrict__ ssx, const float* __restrict__ ssy,
    const float* __restrict__ cutoff, const float* __restrict__ phi,
    float* __restrict__ out)
{
  __shared__ ushort As[BM * BKS];   // 8 KiB
  __shared__ ushort Bs[BN * BKS];   // 8 KiB   (16 KiB total)

  const int tid  = threadIdx.x;
  const int lane = tid & 63;
  const int w    = tid >> 6;
  const int wr = w >> 1, wc = w & 1;
  const int l15 = lane & 15, l16 = lane >> 4;

  // chunked XCD swizzle (R6): xcd = bid&7, local = bid>>3.
  const int bid   = blockIdx.x;
  const int xcd   = bid & 7;
  const int local = bid >> 3;
  const int wk    = local & 31;
  const int bx = xcd * 8 + (wk & 7);           // 64 row-blocks; bx in [8k,8k+8)
  const int by = (local >> 5) * 4 + (wk >> 3); // 32 col-blocks

  // staging: 512 granules (16B) per matrix per step, 2 per thread
  const int i0 = tid, i1 = tid + 256;
  const int r0 = i0 >> 2, r1 = i1 >> 2;
  const int c0 = (i0 & 3) ^ ((r0 >> 1) & 3);   // pre-swizzled source granule
  const int c1 = (i1 & 3) ^ ((r1 >> 1) & 3);
  const ushort* aS0 = xb + (size_t)(bx * BM + r0) * DDIM + c0 * 8;
  const ushort* aS1 = xb + (size_t)(bx * BM + r1) * DDIM + c1 * 8;
  const ushort* bS0 = yb + (size_t)(by * BN + r0) * DDIM + c0 * 8;
  const ushort* bS1 = yb + (size_t)(by * BN + r1) * DDIM + c1 * 8;
  const int d0 = i0 * 8, d1 = i1 * 8;          // linear LDS dest (elements)

  // fragment ds_read offsets (loop-invariant, swizzled)
  int aoff[4], boff[4];
  #pragma unroll
  for (int a = 0; a < 4; a++) {
    int row = wr * 64 + a * 16 + l15;
    aoff[a] = row * BKS + ((l16 ^ ((row >> 1) & 3)) << 3);
  }
  #pragma unroll
  for (int b = 0; b < 4; b++) {
    int col = wc * 64 + b * 16 + l15;
    boff[b] = col * BKS + ((l16 ^ ((col >> 1) & 3)) << 3);
  }

  f32x4 acc[4][4];
  #pragma unroll
  for (int a = 0; a < 4; a++)
    #pragma unroll
    for (int b = 0; b < 4; b++) acc[a][b] = (f32x4)(0.f);

  for (int s = 0; s < NSTEP; ++s) {
    const int ko = s * BKS;
    load_lds16(aS0 + ko, &As[d0]);
    load_lds16(aS1 + ko, &As[d1]);
    load_lds16(bS0 + ko, &Bs[d0]);
    load_lds16(bS1 + ko, &Bs[d1]);
    __syncthreads();  // vmcnt(0) drain + barrier (phase-separated DS pipe)

    bf16x8 af[4], bf[4];
    #pragma unroll
    for (int a = 0; a < 4; a++) af[a] = *(const bf16x8*)&As[aoff[a]];
    #pragma unroll
    for (int b = 0; b < 4; b++) bf[b] = *(const bf16x8*)&Bs[boff[b]];

    #pragma unroll
    for (int a = 0; a < 4; a++)
      #pragma unroll
      for (int b = 0; b < 4; b++)
        acc[a][b] = __builtin_amdgcn_mfma_f32_16x16x32_bf16(af[a], bf[b], acc[a][b], 0, 0, 0);

    __syncthreads();  // WAR: frag reads done before next stage overwrites
  }

  // ---- fused epilogue (R6-proven) ----
  const float cut_c = fminf(fmaxf(cutoff[0], 0.f), 1000.f);
  const float q  = phi[0] * 1.4426950408889634f;   // phi * log2(e)
  const float qc = q * cut_c;
  const int rowBase = bx * BM + wr * 64;
  const int colBase = by * BN + wc * 64;

  float sq_j[4], sy_j[4];
  #pragma unroll
  for (int b = 0; b < 4; b++) {
    int j = colBase + b * 16 + l15;
    sq_j[b] = sqy[j];
    sy_j[b] = ssy[j];
  }
  #pragma unroll
  for (int a = 0; a < 4; a++) {
    float sq_i[4], sx_i[4];
    #pragma unroll
    for (int r = 0; r < 4; r++) {
      int i = rowBase + a * 16 + l16 * 4 + r;
      sq_i[r] = sqx[i];
      sx_i[r] = ssx[i];
    }
    #pragma unroll
    for (int b = 0; b < 4; b++) {
      #pragma unroll
      for (int r = 0; r < 4; r++) {
        int i = rowBase + a * 16 + l16 * 4 + r;
        int j = colBase + b * 16 + l15;
        float dot = acc[a][b][r];
        float d = __builtin_fmaf(-2.f, dot, sq_i[r] + sq_j[b]);
        float s = sx_i[r] * sy_j[b];
        float res = s * __builtin_amdgcn_rcpf(s + d);     // 1/(1+d/s)
        float earg = __builtin_fmaf(-q, res, qc);         // -phi*(res-cut)*log2e
        float u = __builtin_amdgcn_exp2f(earg);
        float o = res * __builtin_amdgcn_rcpf(1.f + u);   // res * sigmoid
        out[(size_t)i * M_ROWS + j] = o;
      }
    }
  }
}

extern "C" void kernel_launch(void* const* d_in, const int* in_sizes, int n_in,
                              void* d_out, int out_size, void* d_ws, size_t ws_size,
                              hipStream_t stream) {
  const float* x       = (const float*)d_in[0];
  const float* y       = (const float*)d_in[1];
  const float* samp_x  = (const float*)d_in[2];
  const float* samp_y  = (const float*)d_in[3];
  const float* scale   = (const float*)d_in[4];
  const float* cutoff  = (const float*)d_in[5];
  const float* phi     = (const float*)d_in[6];
  float* out = (float*)d_out;

  char* p = (char*)d_ws;
  ushort* xb = (ushort*)p; p += (size_t)N_ROWS * DDIM * 2;
  ushort* yb = (ushort*)p; p += (size_t)M_ROWS * DDIM * 2;
  float* sqx = (float*)p;  p += (size_t)N_ROWS * 4;
  float* sqy = (float*)p;  p += (size_t)M_ROWS * 4;
  float* ssx = (float*)p;  p += (size_t)N_ROWS * 4;
  float* ssy = (float*)p;  p += (size_t)M_ROWS * 4;

  prep_kernel<<<(N_ROWS + M_ROWS) / 4, 256, 0, stream>>>(
      x, y, samp_x, samp_y, scale, xb, yb, sqx, sqy, ssx, ssy);

  cauchy_gemm<<<(N_ROWS / BM) * (M_ROWS / BN), 256, 0, stream>>>(
      xb, yb, sqx, sqy, ssx, ssy, cutoff, phi, out);
}